// Round 8
// baseline (130.597 us; speedup 1.0000x reference)
//
#include <hip/hip_runtime.h>
#include <math.h>

#define TW 32
#define TH 32
#define HR 42          // TH + 10 intermediate rows
#define IMG_W 512
#define OUT_W 502      // 512 - 11 + 1
#define CH_STRIDE (3 * IMG_W * IMG_W)
#define NBLK 4096      // 16 x 16 x 16

// Gaussian 11-tap, sigma=1.5, normalized offline at double precision.
__device__ __constant__ const float GW[11] = {
    0.00102838f, 0.00759876f, 0.03600080f, 0.10936070f, 0.21300550f,
    0.26601170f,
    0.21300550f, 0.10936070f, 0.03600080f, 0.00759876f, 0.00102838f
};

// R8: R7 structure (measured best, ~27 us kernel) + float2-interleaved LDS
// fields (m1,m2) and (x2,y2) -> phase-2 reads 70xb32 -> 28xb64+14xb32, and
// float2 arithmetic to trigger v_pk_fma_f32 in both phases.
// Geometry: 32x32 tile, 26.9 KB LDS -> 6 blocks/CU (binding resource per R5).
// Epilogue: partial[] + finalize (NO same-address atomics -> R6 lesson).
__global__ __launch_bounds__(256) void ssim_main_kernel(
    const float* __restrict__ sr_img,
    const float* __restrict__ hr_img,
    float* __restrict__ partial)
{
    __shared__ __align__(16) float2 hfA[HR][TW];  // (m1, m2)   10752 B
    __shared__ __align__(16) float2 hfB[HR][TW];  // (x2, y2)   10752 B
    __shared__ __align__(16) float  hfC[HR][TW];  // xy          5376 B
    __shared__ float red[4];                      // total 26896 B -> 6 blk/CU

    const int t  = threadIdx.x;
    const int x0 = blockIdx.x * TW;
    const int y0 = blockIdx.y * TH;
    const int b  = blockIdx.z;

    const float* __restrict__ hrp = hr_img + (size_t)b * CH_STRIDE;  // channel 0
    const float* __restrict__ srp = sr_img + (size_t)b * CH_STRIDE;

    // ---------- Phase 1: horizontal 11-tap, direct from global ----------
    if (t < 168) {
        int r  = t >> 2;          // 0..41
        int c0 = (t & 3) * 8;     // 0,8,16,24
        int gy = y0 + r; if (gy > IMG_W - 1) gy = IMG_W - 1;
        // 16B-aligned; right-edge spill stays inside the allocation and only
        // feeds discarded (ox >= 502) outputs.
        const float4* hrow = (const float4*)(hrp + (size_t)gy * IMG_W + x0 + c0);
        const float4* srow = (const float4*)(srp + (size_t)gy * IMG_W + x0 + c0);

        // hs[j] = (hr, sr) packed -> v_pk_fma_f32 on the tap loops
        float2 hs[20];
#pragma unroll
        for (int q = 0; q < 5; ++q) {
            float4 va = hrow[q];
            float4 vb = srow[q];
            hs[4*q+0] = make_float2(va.x, vb.x);
            hs[4*q+1] = make_float2(va.y, vb.y);
            hs[4*q+2] = make_float2(va.z, vb.z);
            hs[4*q+3] = make_float2(va.w, vb.w);
        }

        float2 m12[8], sq[8];     // (m1,m2), (x2,y2)
        float  xy[8];
#pragma unroll
        for (int j = 0; j < 8; ++j) {
            m12[j] = make_float2(0.f, 0.f);
            sq[j]  = make_float2(0.f, 0.f);
            xy[j]  = 0.f;
        }
#pragma unroll
        for (int k = 0; k < 11; ++k) {
            float wk = GW[k];
#pragma unroll
            for (int j = 0; j < 8; ++j) {
                float2 v = hs[j + k];
                float2 wv = make_float2(wk * v.x, wk * v.y);     // packed mul
                m12[j].x += wv.x;        m12[j].y += wv.y;       // packed fma
                sq[j].x  += wv.x * v.x;  sq[j].y  += wv.y * v.y; // packed fma
                xy[j]    += wv.x * v.y;                          // scalar fma
            }
        }
        // 16B stores: 2 float2s per b128, c0 even -> aligned
#pragma unroll
        for (int j = 0; j < 8; j += 2) {
            *(float4*)&hfA[r][c0 + j] = make_float4(m12[j].x, m12[j].y, m12[j+1].x, m12[j+1].y);
            *(float4*)&hfB[r][c0 + j] = make_float4(sq[j].x,  sq[j].y,  sq[j+1].x,  sq[j+1].y);
        }
        *(float4*)&hfC[r][c0]     = make_float4(xy[0], xy[1], xy[2], xy[3]);
        *(float4*)&hfC[r][c0 + 4] = make_float4(xy[4], xy[5], xy[6], xy[7]);
    }
    __syncthreads();

    // ---------- Phase 2: vertical 11-tap, 4-row strips, all 256 threads ----------
    const float C1 = 1e-4f, C2 = 9e-4f;
    float local = 0.f;
    {
        int c  = t & 31;
        int r0 = (t >> 5) * 4;    // 0,4,...,28

        float2 am12[4], asq[4];
        float  axy[4];
#pragma unroll
        for (int j = 0; j < 4; ++j) {
            am12[j] = make_float2(0.f, 0.f);
            asq[j]  = make_float2(0.f, 0.f);
            axy[j]  = 0.f;
        }

#pragma unroll
        for (int i = 0; i < 14; ++i) {
            float2 v12 = hfA[r0 + i][c];   // ds_read_b64
            float2 vsq = hfB[r0 + i][c];   // ds_read_b64
            float  vxy = hfC[r0 + i][c];   // ds_read_b32
#pragma unroll
            for (int j = 0; j < 4; ++j) {
                int k = i - j;             // compile-time resolved
                if (k >= 0 && k <= 10) {
                    float wk = GW[k];
                    am12[j].x += wk * v12.x;  am12[j].y += wk * v12.y;  // packed
                    asq[j].x  += wk * vsq.x;  asq[j].y  += wk * vsq.y;  // packed
                    axy[j]    += wk * vxy;
                }
            }
        }

        int ox = x0 + c;
#pragma unroll
        for (int j = 0; j < 4; ++j) {
            int oy = y0 + r0 + j;
            if (oy < OUT_W && ox < OUT_W) {
                float m1 = am12[j].x, m2 = am12[j].y;
                float mu1s = m1 * m1, mu2s = m2 * m2, m12v = m1 * m2;
                float s1 = asq[j].x - mu1s, s2 = asq[j].y - mu2s, s12 = axy[j] - m12v;
                float num = (2.f * m12v + C1) * (2.f * s12 + C2);
                float den = (mu1s + mu2s + C1) * (s1 + s2 + C2);
                local += num * __builtin_amdgcn_rcpf(den);   // |rel err| ~2e-7
            }
        }
    }

    // ---------- Reduction: wave shuffle + tiny LDS ----------
#pragma unroll
    for (int off = 32; off > 0; off >>= 1)
        local += __shfl_down(local, off);
    if ((t & 63) == 0) red[t >> 6] = local;
    __syncthreads();
    if (t == 0) {
        int blk = (blockIdx.z * gridDim.y + blockIdx.y) * gridDim.x + blockIdx.x;
        partial[blk] = red[0] + red[1] + red[2] + red[3];
    }
}

__global__ __launch_bounds__(256) void ssim_finalize(
    const float* __restrict__ partial, float* __restrict__ out)
{
    __shared__ float red[4];
    int t = threadIdx.x;
    float s = 0.f;
#pragma unroll
    for (int i = 0; i < NBLK / 256; ++i)
        s += partial[t + i * 256];
#pragma unroll
    for (int off = 32; off > 0; off >>= 1)
        s += __shfl_down(s, off);
    if ((t & 63) == 0) red[t >> 6] = s;
    __syncthreads();
    if (t == 0)
        out[0] = (red[0] + red[1] + red[2] + red[3]) * (1.0f / (16.0f * 502.0f * 502.0f));
}

extern "C" void kernel_launch(void* const* d_in, const int* in_sizes, int n_in,
                              void* d_out, int out_size, void* d_ws, size_t ws_size,
                              hipStream_t stream)
{
    const float* sr = (const float*)d_in[0];  // sr_image
    const float* hr = (const float*)d_in[1];  // hr_image
    float* out = (float*)d_out;
    float* partial = (float*)d_ws;            // 4096 floats, fully overwritten

    dim3 grid(16, 16, 16);   // x tiles, y tiles, batch
    ssim_main_kernel<<<grid, 256, 0, stream>>>(sr, hr, partial);
    ssim_finalize<<<1, 256, 0, stream>>>(partial, out);
}